// Round 10
// baseline (703.588 us; speedup 1.0000x reference)
//
#include <hip/hip_runtime.h>

#define T_STEPS 512
#define B_ENV   256
#define D_IN    64
#define H_DIM   128
#define G4      512   // 4*H gate rows

typedef _Float16 h2v __attribute__((ext_vector_type(2)));
typedef _Float16 h8v __attribute__((ext_vector_type(8)));
typedef float    f4v __attribute__((ext_vector_type(4)));

__device__ __forceinline__ float dot2(h2v a, h2v b, float c) {
#if __has_builtin(__builtin_amdgcn_fdot2)
    return __builtin_amdgcn_fdot2(a, b, c, false);
#else
    return c + (float)a.x * (float)b.x + (float)a.y * (float)b.y;
#endif
}

__device__ __forceinline__ h2v pack16(float a, float b) {
#if __has_builtin(__builtin_amdgcn_cvt_pkrtz)
    union { __fp16 __attribute__((ext_vector_type(2))) r; h2v h; } u;
    u.r = __builtin_amdgcn_cvt_pkrtz(a, b);
    return u.h;
#else
    h2v p; p.x = (_Float16)a; p.y = (_Float16)b; return p;
#endif
}

__device__ __forceinline__ float fast_rcp(float x) {
#if __has_builtin(__builtin_amdgcn_rcpf)
    return __builtin_amdgcn_rcpf(x);
#else
    return 1.0f / x;
#endif
}
__device__ __forceinline__ float sigm(float x)   { return fast_rcp(1.0f + __expf(-x)); }
__device__ __forceinline__ float tanh_f(float x) { float e = __expf(2.0f * x); return 1.0f - 2.0f * fast_rcp(e + 1.0f); }

// DPP quad_perm ops (VALU pipe — never LDS).
template <int CTRL>
__device__ __forceinline__ float dpp_mov(float v) {
    int s = __builtin_amdgcn_update_dpp(
        0, __builtin_bit_cast(int, v), CTRL, 0xF, 0xF, true);
    return __builtin_bit_cast(float, s);
}
__device__ __forceinline__ float quad_allreduce(float v) {
    v += dpp_mov<0xB1>(v);   // quad_perm(1,0,3,2): xor1
    v += dpp_mov<0x4E>(v);   // quad_perm(2,3,0,1): xor2
    return v;
}

// Barrier draining LDS ops only — global loads/stores stay in flight.
__device__ __forceinline__ void sync_lds() {
    asm volatile("s_waitcnt lgkmcnt(0)" ::: "memory");
    __builtin_amdgcn_s_barrier();
    asm volatile("" ::: "memory");
}

// One-wave async global->LDS: 64 lanes x 4B = 256B (one full x row).
__device__ __forceinline__ void async_load_row(const float* gsrc, float* ldst) {
    __builtin_amdgcn_global_load_lds(
        (const __attribute__((address_space(1))) unsigned int*)gsrc,
        (__attribute__((address_space(3))) unsigned int*)ldst, 4, 0, 0);
}

// Scan: TWO envs per 1024-thread block (grid 128, one block/CU).
// Waves 0-7 run env blockIdx*2, waves 8-15 run env blockIdx*2+1 — two
// fully independent R9-structure recurrences sharing only the block
// barrier (same cadence). 4 waves/SIMD: env A's dependency-chain stalls
// are filled by env B's issue. Requires VGPR <= 128 (R9 measured 108).
// Per-env structure (unchanged from R9): thread (j=l>>2, qq=l&3) owns
// k-quarter qq of gate rows {j,128+j,256+j,384+j} of W_hh/W_ih in f16
// registers; 4+2 per-lane ds_read_b128 -> 96 dot2 -> DPP quad allreduce
// -> lane qq activates gate qq -> DPP broadcast -> replicated cell
// update -> qq==0 writes h16 (pre-scaled by smask[t+1]) + raw h to
// d_out. Per-half wave 0 drives the x ring (global_load_lds x_{t+3},
// f32->f16 convert of x_{t+1}, counted vmcnt(1)). ONE lgkm barrier/step.
__global__ __launch_bounds__(1024, 4)
void ppo_lstm_scan(const float* __restrict__ x,      // [T,B,D]
                   const float* __restrict__ done,   // [T,B]
                   const float* __restrict__ h0,     // [B,H]
                   const float* __restrict__ c0,     // [B,H]
                   const float* __restrict__ W_ih,   // [4H,D]
                   const float* __restrict__ b_ih,   // [4H]
                   const float* __restrict__ W_hh,   // [4H,H]
                   const float* __restrict__ b_hh,   // [4H]
                   float* __restrict__ hs)           // [T,B,H] = d_out (raw h)
{
    const int tid  = threadIdx.x;
    const int half = tid >> 9;            // which env within the block
    const int l    = tid & 511;           // local tid within env
    const int b    = blockIdx.x * 2 + half;
    const int lane = tid & 63;
    const int lwid = (tid >> 6) & 7;      // wave id within half
    const int qq   = l & 3;
    const int j    = l >> 2;

    __shared__ alignas(16) h2v   h16[2][2][H_DIM / 2]; // per-half h f16, dbuf
    __shared__ alignas(16) h2v   x16[2][2][D_IN / 2];  // per-half x f16, dbuf
    __shared__ alignas(16) float smask[2][T_STEPS];    // per-half 1-done
    __shared__ alignas(16) float xring[2][4][D_IN];    // per-half x f32 ring

    // ---- one-time: weight slices -> registers (f16; same for both halves) ----
    h2v whh[64];   // gate g, k-quarter qq: 16 h2v each
    h2v wih[32];   // gate g, x-quarter qq: 8 h2v each
    #pragma unroll
    for (int g = 0; g < 4; ++g) {
        const float* wr = W_hh + (size_t)(g * H_DIM + j) * H_DIM + qq * 32;
        #pragma unroll
        for (int c = 0; c < 16; ++c)
            whh[g * 16 + c] = pack16(wr[2 * c], wr[2 * c + 1]);
        const float* wr2 = W_ih + (size_t)(g * H_DIM + j) * D_IN + qq * 16;
        #pragma unroll
        for (int c = 0; c < 8; ++c)
            wih[g * 8 + c] = pack16(wr2[2 * c], wr2[2 * c + 1]);
    }
    const int   r_own    = qq * H_DIM + j;
    const float bias_own = b_ih[r_own] + b_hh[r_own];
    float       c_reg    = c0[b * H_DIM + j];

    // ---- one-time: done mask, h0 (pre-scaled), x ring prologue ----
    smask[half][l] = 1.0f - done[(size_t)l * B_ENV + b];   // l == t
    if (l < 64) {
        const float sm0 = 1.0f - done[b];
        const float* hp = h0 + b * H_DIM;
        h16[half][0][l] = pack16(hp[2 * l] * sm0, hp[2 * l + 1] * sm0);
    }
    if (lwid == 0) {
        #pragma unroll
        for (int s = 0; s < 3; ++s)
            async_load_row(x + ((size_t)s * B_ENV + b) * D_IN + lane,
                           &xring[half][s][0]);
    }
    __syncthreads();                 // full drain once: x0..x2 landed
    if (lwid == 0 && lane < 32) {    // convert x0 -> x16[half][0]
        float2 v = *reinterpret_cast<const float2*>(&xring[half][0][2 * lane]);
        x16[half][0][lane] = pack16(v.x, v.y);
    }
    sync_lds();

    for (int t = 0; t < T_STEPS; ++t) {
        const int rb = t & 1, wb = rb ^ 1;

        if (lwid == 0) {
            const int t3 = (t + 3 < T_STEPS) ? (t + 3) : (T_STEPS - 1);
            async_load_row(x + ((size_t)t3 * B_ENV + b) * D_IN + lane,
                           &xring[half][(t + 3) & 3][0]);
            if (lane < 32) {   // convert x_{t+1} (landed: last step's vmcnt)
                float2 v = *reinterpret_cast<const float2*>(
                    &xring[half][(t + 1) & 3][2 * lane]);
                x16[half][wb][lane] = pack16(v.x, v.y);
            }
        }

        // ---- k-quarter dots: 4 b128 (h) + 2 b128 (x), per-lane distinct ----
        const h8v* hp8 = reinterpret_cast<const h8v*>(&h16[half][rb][qq * 16]);
        const h8v* xp8 = reinterpret_cast<const h8v*>(&x16[half][rb][qq * 8]);
        float s0 = 0.f, s1 = 0.f, s2 = 0.f, s3 = 0.f;
        #pragma unroll
        for (int c4 = 0; c4 < 4; ++c4) {
            union { h8v v; h2v p[4]; } u;
            u.v = hp8[c4];
            #pragma unroll
            for (int pp = 0; pp < 4; ++pp) {
                s0 = dot2(whh[      c4 * 4 + pp], u.p[pp], s0);
                s1 = dot2(whh[16 +  c4 * 4 + pp], u.p[pp], s1);
                s2 = dot2(whh[32 +  c4 * 4 + pp], u.p[pp], s2);
                s3 = dot2(whh[48 +  c4 * 4 + pp], u.p[pp], s3);
            }
        }
        #pragma unroll
        for (int c4 = 0; c4 < 2; ++c4) {
            union { h8v v; h2v p[4]; } u;
            u.v = xp8[c4];
            #pragma unroll
            for (int pp = 0; pp < 4; ++pp) {
                s0 = dot2(wih[      c4 * 4 + pp], u.p[pp], s0);
                s1 = dot2(wih[ 8 +  c4 * 4 + pp], u.p[pp], s1);
                s2 = dot2(wih[16 +  c4 * 4 + pp], u.p[pp], s2);
                s3 = dot2(wih[24 +  c4 * 4 + pp], u.p[pp], s3);
            }
        }

        // ---- quad allreduce (h pre-masked -> no dm in dot path) ----
        s0 = quad_allreduce(s0);
        s1 = quad_allreduce(s1);
        s2 = quad_allreduce(s2);
        s3 = quad_allreduce(s3);

        // ---- lane qq activates its own gate, then quad-broadcast ----
        const float s01 = (qq & 1) ? s1 : s0;
        const float s23 = (qq & 1) ? s3 : s2;
        const float gs  = ((qq & 2) ? s23 : s01) + bias_own;
        const float av  = (qq == 2) ? tanh_f(gs) : sigm(gs);
        const float ai  = dpp_mov<0x00>(av);
        const float af  = dpp_mov<0x55>(av);
        const float ag  = dpp_mov<0xAA>(av);
        const float ao  = dpp_mov<0xFF>(av);

        // ---- cell update, replicated (bit-identical) in quad ----
        const float dm = smask[half][t];
        const float cn = af * (c_reg * dm) + ai * ag;
        c_reg = cn;
        const float hn = ao * tanh_f(cn);

        if (lwid == 0) {
            // counted wait BEFORE this wave's store: proves x_{t+2} landed.
            asm volatile("s_waitcnt vmcnt(1)" ::: "memory");
        }
        if (qq == 0) {
            const float smn = smask[half][(t + 1 < T_STEPS) ? (t + 1) : (T_STEPS - 1)];
            reinterpret_cast<_Float16*>(h16[half][wb])[j] = (_Float16)(hn * smn);
            hs[((size_t)t * B_ENV + b) * H_DIM + j] = hn;   // stays in flight
        }
        sync_lds();   // single barrier: h_t, x16_{t+1}, x_{t+2} all published
    }
}

// In-place row projection: out[r,:] = out_row @ W_hid^T + b_hid.
// 1024 blocks x 256 threads; block owns 128 rows (disjoint -> in-place safe).
#define PADK 68
__global__ __launch_bounds__(256)
void ppo_proj(const float* __restrict__ W_hid,   // [H,H]
              const float* __restrict__ b_hid,   // [H]
              float* __restrict__ out)           // [T*B, H] in-place
{
    __shared__ h2v wl[H_DIM][PADK];
    __shared__ h2v hl[H_DIM][PADK];
    const int tid = threadIdx.x;
    const int rg  = tid >> 4;
    const int cg  = tid & 15;

    const size_t r0 = (size_t)blockIdx.x * H_DIM;

    #pragma unroll
    for (int i = 0; i < 16; ++i) {
        const int idx = tid + 256 * i;
        const int r = idx >> 5, cc = idx & 31;
        f4v v = *reinterpret_cast<const f4v*>(W_hid + 4 * (size_t)idx);
        wl[r][2 * cc]     = pack16(v.x, v.y);
        wl[r][2 * cc + 1] = pack16(v.z, v.w);
    }
    #pragma unroll
    for (int i = 0; i < 16; ++i) {
        const int idx = tid + 256 * i;
        const int r = idx >> 5, cc = idx & 31;
        f4v v = *reinterpret_cast<const f4v*>(out + (r0 + r) * H_DIM + 4 * cc);
        hl[r][2 * cc]     = pack16(v.x, v.y);
        hl[r][2 * cc + 1] = pack16(v.z, v.w);
    }
    float bcol[8];
    #pragma unroll
    for (int jj = 0; jj < 8; ++jj) bcol[jj] = b_hid[cg + 16 * jj];
    __syncthreads();

    float acc[8][8];
    #pragma unroll
    for (int i = 0; i < 8; ++i)
        #pragma unroll
        for (int jj = 0; jj < 8; ++jj) acc[i][jj] = 0.f;

    for (int kq = 0; kq < 16; ++kq) {
        union { h8v v; h2v p[4]; } hv[8], wv[8];
        #pragma unroll
        for (int i = 0; i < 8; ++i)
            hv[i].v = *reinterpret_cast<const h8v*>(&hl[rg * 8 + i][4 * kq]);
        #pragma unroll
        for (int jj = 0; jj < 8; ++jj)
            wv[jj].v = *reinterpret_cast<const h8v*>(&wl[cg + 16 * jj][4 * kq]);
        #pragma unroll
        for (int i = 0; i < 8; ++i)
            #pragma unroll
            for (int jj = 0; jj < 8; ++jj) {
                acc[i][jj] = dot2(hv[i].p[0], wv[jj].p[0], acc[i][jj]);
                acc[i][jj] = dot2(hv[i].p[1], wv[jj].p[1], acc[i][jj]);
                acc[i][jj] = dot2(hv[i].p[2], wv[jj].p[2], acc[i][jj]);
                acc[i][jj] = dot2(hv[i].p[3], wv[jj].p[3], acc[i][jj]);
            }
    }

    #pragma unroll
    for (int i = 0; i < 8; ++i)
        #pragma unroll
        for (int jj = 0; jj < 8; ++jj)
            out[(r0 + rg * 8 + i) * H_DIM + cg + 16 * jj] = acc[i][jj] + bcol[jj];
}

extern "C" void kernel_launch(void* const* d_in, const int* in_sizes, int n_in,
                              void* d_out, int out_size, void* d_ws, size_t ws_size,
                              hipStream_t stream) {
    const float* x     = (const float*)d_in[0];
    const float* done  = (const float*)d_in[1];
    const float* h0    = (const float*)d_in[2];
    const float* c0    = (const float*)d_in[3];
    const float* W_ih  = (const float*)d_in[4];
    const float* b_ih  = (const float*)d_in[5];
    const float* W_hh  = (const float*)d_in[6];
    const float* b_hh  = (const float*)d_in[7];
    const float* W_hid = (const float*)d_in[8];
    const float* b_hid = (const float*)d_in[9];
    float* out = (float*)d_out;
    (void)d_ws; (void)ws_size; (void)out_size; (void)n_in; (void)in_sizes;

    hipLaunchKernelGGL(ppo_lstm_scan, dim3(B_ENV / 2), dim3(1024), 0, stream,
                       x, done, h0, c0, W_ih, b_ih, W_hh, b_hh, out);
    hipLaunchKernelGGL(ppo_proj, dim3((T_STEPS * B_ENV) / H_DIM), dim3(256), 0, stream,
                       W_hid, b_hid, out);
}

// Round 11
// 701.497 us; speedup vs baseline: 1.0030x; 1.0030x over previous
//
#include <hip/hip_runtime.h>

#define T_STEPS 512
#define B_ENV   256
#define D_IN    64
#define H_DIM   128
#define G4      512   // 4*H gate rows

typedef _Float16 h2v __attribute__((ext_vector_type(2)));
typedef _Float16 h8v __attribute__((ext_vector_type(8)));
typedef float    f4v __attribute__((ext_vector_type(4)));

__device__ __forceinline__ float dot2(h2v a, h2v b, float c) {
#if __has_builtin(__builtin_amdgcn_fdot2)
    return __builtin_amdgcn_fdot2(a, b, c, false);
#else
    return c + (float)a.x * (float)b.x + (float)a.y * (float)b.y;
#endif
}

__device__ __forceinline__ h2v pack16(float a, float b) {
#if __has_builtin(__builtin_amdgcn_cvt_pkrtz)
    union { __fp16 __attribute__((ext_vector_type(2))) r; h2v h; } u;
    u.r = __builtin_amdgcn_cvt_pkrtz(a, b);
    return u.h;
#else
    h2v p; p.x = (_Float16)a; p.y = (_Float16)b; return p;
#endif
}

__device__ __forceinline__ float fast_rcp(float x) {
#if __has_builtin(__builtin_amdgcn_rcpf)
    return __builtin_amdgcn_rcpf(x);
#else
    return 1.0f / x;
#endif
}
__device__ __forceinline__ float sigm(float x)   { return fast_rcp(1.0f + __expf(-x)); }
__device__ __forceinline__ float tanh_f(float x) { float e = __expf(2.0f * x); return 1.0f - 2.0f * fast_rcp(e + 1.0f); }

// DPP quad_perm ops (VALU pipe — never LDS).
template <int CTRL>
__device__ __forceinline__ float dpp_mov(float v) {
    int s = __builtin_amdgcn_update_dpp(
        0, __builtin_bit_cast(int, v), CTRL, 0xF, 0xF, true);
    return __builtin_bit_cast(float, s);
}
__device__ __forceinline__ float quad_allreduce(float v) {
    v += dpp_mov<0xB1>(v);   // quad_perm(1,0,3,2): xor1
    v += dpp_mov<0x4E>(v);   // quad_perm(2,3,0,1): xor2
    return v;
}

// Barrier draining LDS ops only — global loads/stores stay in flight.
__device__ __forceinline__ void sync_lds() {
    asm volatile("s_waitcnt lgkmcnt(0)" ::: "memory");
    __builtin_amdgcn_s_barrier();
    asm volatile("" ::: "memory");
}

// One-wave async global->LDS: 64 lanes x 4B = 256B (one full x row).
__device__ __forceinline__ void async_load_row(const float* gsrc, float* ldst) {
    __builtin_amdgcn_global_load_lds(
        (const __attribute__((address_space(1))) unsigned int*)gsrc,
        (__attribute__((address_space(3))) unsigned int*)ldst, 4, 0, 0);
}

// Scan: TWO envs per 1024-thread block (grid 128, ONE block per CU).
// NOTE __launch_bounds__ 2nd arg is min BLOCKS/CU (CUDA semantics):
// (1024,1) -> 16 waves/CU = 4 waves/SIMD, VGPR cap 128. R9's identical
// per-env kernel measured 108 VGPRs, so this fits WITHOUT spilling
// (R10's (1024,4) forced cap 64 and spilled -> voided the experiment).
// Waves 0-7 run env blockIdx*2, waves 8-15 run env blockIdx*2+1 — two
// independent R9-structure recurrences sharing only the block barrier.
// Env A's dependency-chain stalls are filled by env B's issue on the
// same SIMD. Per-env structure unchanged from R9.
__global__ __launch_bounds__(1024, 1)
void ppo_lstm_scan(const float* __restrict__ x,      // [T,B,D]
                   const float* __restrict__ done,   // [T,B]
                   const float* __restrict__ h0,     // [B,H]
                   const float* __restrict__ c0,     // [B,H]
                   const float* __restrict__ W_ih,   // [4H,D]
                   const float* __restrict__ b_ih,   // [4H]
                   const float* __restrict__ W_hh,   // [4H,H]
                   const float* __restrict__ b_hh,   // [4H]
                   float* __restrict__ hs)           // [T,B,H] = d_out (raw h)
{
    const int tid  = threadIdx.x;
    const int half = tid >> 9;            // which env within the block
    const int l    = tid & 511;           // local tid within env
    const int b    = blockIdx.x * 2 + half;
    const int lane = tid & 63;
    const int lwid = (tid >> 6) & 7;      // wave id within half
    const int qq   = l & 3;
    const int j    = l >> 2;

    __shared__ alignas(16) h2v   h16[2][2][H_DIM / 2]; // per-half h f16, dbuf
    __shared__ alignas(16) h2v   x16[2][2][D_IN / 2];  // per-half x f16, dbuf
    __shared__ alignas(16) float smask[2][T_STEPS];    // per-half 1-done
    __shared__ alignas(16) float xring[2][4][D_IN];    // per-half x f32 ring

    // ---- one-time: weight slices -> registers (f16; same for both halves) ----
    h2v whh[64];   // gate g, k-quarter qq: 16 h2v each
    h2v wih[32];   // gate g, x-quarter qq: 8 h2v each
    #pragma unroll
    for (int g = 0; g < 4; ++g) {
        const float* wr = W_hh + (size_t)(g * H_DIM + j) * H_DIM + qq * 32;
        #pragma unroll
        for (int c = 0; c < 16; ++c)
            whh[g * 16 + c] = pack16(wr[2 * c], wr[2 * c + 1]);
        const float* wr2 = W_ih + (size_t)(g * H_DIM + j) * D_IN + qq * 16;
        #pragma unroll
        for (int c = 0; c < 8; ++c)
            wih[g * 8 + c] = pack16(wr2[2 * c], wr2[2 * c + 1]);
    }
    const int   r_own    = qq * H_DIM + j;
    const float bias_own = b_ih[r_own] + b_hh[r_own];
    float       c_reg    = c0[b * H_DIM + j];

    // ---- one-time: done mask, h0 (pre-scaled), x ring prologue ----
    smask[half][l] = 1.0f - done[(size_t)l * B_ENV + b];   // l == t
    if (l < 64) {
        const float sm0 = 1.0f - done[b];
        const float* hp = h0 + b * H_DIM;
        h16[half][0][l] = pack16(hp[2 * l] * sm0, hp[2 * l + 1] * sm0);
    }
    if (lwid == 0) {
        #pragma unroll
        for (int s = 0; s < 3; ++s)
            async_load_row(x + ((size_t)s * B_ENV + b) * D_IN + lane,
                           &xring[half][s][0]);
    }
    __syncthreads();                 // full drain once: x0..x2 landed
    if (lwid == 0 && lane < 32) {    // convert x0 -> x16[half][0]
        float2 v = *reinterpret_cast<const float2*>(&xring[half][0][2 * lane]);
        x16[half][0][lane] = pack16(v.x, v.y);
    }
    sync_lds();

    for (int t = 0; t < T_STEPS; ++t) {
        const int rb = t & 1, wb = rb ^ 1;

        if (lwid == 0) {
            const int t3 = (t + 3 < T_STEPS) ? (t + 3) : (T_STEPS - 1);
            async_load_row(x + ((size_t)t3 * B_ENV + b) * D_IN + lane,
                           &xring[half][(t + 3) & 3][0]);
            if (lane < 32) {   // convert x_{t+1} (landed: last step's vmcnt)
                float2 v = *reinterpret_cast<const float2*>(
                    &xring[half][(t + 1) & 3][2 * lane]);
                x16[half][wb][lane] = pack16(v.x, v.y);
            }
        }

        // ---- k-quarter dots: 4 b128 (h) + 2 b128 (x), per-lane distinct ----
        const h8v* hp8 = reinterpret_cast<const h8v*>(&h16[half][rb][qq * 16]);
        const h8v* xp8 = reinterpret_cast<const h8v*>(&x16[half][rb][qq * 8]);
        float s0 = 0.f, s1 = 0.f, s2 = 0.f, s3 = 0.f;
        #pragma unroll
        for (int c4 = 0; c4 < 4; ++c4) {
            union { h8v v; h2v p[4]; } u;
            u.v = hp8[c4];
            #pragma unroll
            for (int pp = 0; pp < 4; ++pp) {
                s0 = dot2(whh[      c4 * 4 + pp], u.p[pp], s0);
                s1 = dot2(whh[16 +  c4 * 4 + pp], u.p[pp], s1);
                s2 = dot2(whh[32 +  c4 * 4 + pp], u.p[pp], s2);
                s3 = dot2(whh[48 +  c4 * 4 + pp], u.p[pp], s3);
            }
        }
        #pragma unroll
        for (int c4 = 0; c4 < 2; ++c4) {
            union { h8v v; h2v p[4]; } u;
            u.v = xp8[c4];
            #pragma unroll
            for (int pp = 0; pp < 4; ++pp) {
                s0 = dot2(wih[      c4 * 4 + pp], u.p[pp], s0);
                s1 = dot2(wih[ 8 +  c4 * 4 + pp], u.p[pp], s1);
                s2 = dot2(wih[16 +  c4 * 4 + pp], u.p[pp], s2);
                s3 = dot2(wih[24 +  c4 * 4 + pp], u.p[pp], s3);
            }
        }

        // ---- quad allreduce (h pre-masked -> no dm in dot path) ----
        s0 = quad_allreduce(s0);
        s1 = quad_allreduce(s1);
        s2 = quad_allreduce(s2);
        s3 = quad_allreduce(s3);

        // ---- lane qq activates its own gate, then quad-broadcast ----
        const float s01 = (qq & 1) ? s1 : s0;
        const float s23 = (qq & 1) ? s3 : s2;
        const float gs  = ((qq & 2) ? s23 : s01) + bias_own;
        const float av  = (qq == 2) ? tanh_f(gs) : sigm(gs);
        const float ai  = dpp_mov<0x00>(av);
        const float af  = dpp_mov<0x55>(av);
        const float ag  = dpp_mov<0xAA>(av);
        const float ao  = dpp_mov<0xFF>(av);

        // ---- cell update, replicated (bit-identical) in quad ----
        const float dm = smask[half][t];
        const float cn = af * (c_reg * dm) + ai * ag;
        c_reg = cn;
        const float hn = ao * tanh_f(cn);

        if (lwid == 0) {
            // counted wait BEFORE this wave's store: proves x_{t+2} landed.
            asm volatile("s_waitcnt vmcnt(1)" ::: "memory");
        }
        if (qq == 0) {
            const float smn = smask[half][(t + 1 < T_STEPS) ? (t + 1) : (T_STEPS - 1)];
            reinterpret_cast<_Float16*>(h16[half][wb])[j] = (_Float16)(hn * smn);
            hs[((size_t)t * B_ENV + b) * H_DIM + j] = hn;   // stays in flight
        }
        sync_lds();   // single barrier: h_t, x16_{t+1}, x_{t+2} all published
    }
}

// In-place row projection: out[r,:] = out_row @ W_hid^T + b_hid.
// 1024 blocks x 256 threads; block owns 128 rows (disjoint -> in-place safe).
#define PADK 68
__global__ __launch_bounds__(256)
void ppo_proj(const float* __restrict__ W_hid,   // [H,H]
              const float* __restrict__ b_hid,   // [H]
              float* __restrict__ out)           // [T*B, H] in-place
{
    __shared__ h2v wl[H_DIM][PADK];
    __shared__ h2v hl[H_DIM][PADK];
    const int tid = threadIdx.x;
    const int rg  = tid >> 4;
    const int cg  = tid & 15;

    const size_t r0 = (size_t)blockIdx.x * H_DIM;

    #pragma unroll
    for (int i = 0; i < 16; ++i) {
        const int idx = tid + 256 * i;
        const int r = idx >> 5, cc = idx & 31;
        f4v v = *reinterpret_cast<const f4v*>(W_hid + 4 * (size_t)idx);
        wl[r][2 * cc]     = pack16(v.x, v.y);
        wl[r][2 * cc + 1] = pack16(v.z, v.w);
    }
    #pragma unroll
    for (int i = 0; i < 16; ++i) {
        const int idx = tid + 256 * i;
        const int r = idx >> 5, cc = idx & 31;
        f4v v = *reinterpret_cast<const f4v*>(out + (r0 + r) * H_DIM + 4 * cc);
        hl[r][2 * cc]     = pack16(v.x, v.y);
        hl[r][2 * cc + 1] = pack16(v.z, v.w);
    }
    float bcol[8];
    #pragma unroll
    for (int jj = 0; jj < 8; ++jj) bcol[jj] = b_hid[cg + 16 * jj];
    __syncthreads();

    float acc[8][8];
    #pragma unroll
    for (int i = 0; i < 8; ++i)
        #pragma unroll
        for (int jj = 0; jj < 8; ++jj) acc[i][jj] = 0.f;

    for (int kq = 0; kq < 16; ++kq) {
        union { h8v v; h2v p[4]; } hv[8], wv[8];
        #pragma unroll
        for (int i = 0; i < 8; ++i)
            hv[i].v = *reinterpret_cast<const h8v*>(&hl[rg * 8 + i][4 * kq]);
        #pragma unroll
        for (int jj = 0; jj < 8; ++jj)
            wv[jj].v = *reinterpret_cast<const h8v*>(&wl[cg + 16 * jj][4 * kq]);
        #pragma unroll
        for (int i = 0; i < 8; ++i)
            #pragma unroll
            for (int jj = 0; jj < 8; ++jj) {
                acc[i][jj] = dot2(hv[i].p[0], wv[jj].p[0], acc[i][jj]);
                acc[i][jj] = dot2(hv[i].p[1], wv[jj].p[1], acc[i][jj]);
                acc[i][jj] = dot2(hv[i].p[2], wv[jj].p[2], acc[i][jj]);
                acc[i][jj] = dot2(hv[i].p[3], wv[jj].p[3], acc[i][jj]);
            }
    }

    #pragma unroll
    for (int i = 0; i < 8; ++i)
        #pragma unroll
        for (int jj = 0; jj < 8; ++jj)
            out[(r0 + rg * 8 + i) * H_DIM + cg + 16 * jj] = acc[i][jj] + bcol[jj];
}

extern "C" void kernel_launch(void* const* d_in, const int* in_sizes, int n_in,
                              void* d_out, int out_size, void* d_ws, size_t ws_size,
                              hipStream_t stream) {
    const float* x     = (const float*)d_in[0];
    const float* done  = (const float*)d_in[1];
    const float* h0    = (const float*)d_in[2];
    const float* c0    = (const float*)d_in[3];
    const float* W_ih  = (const float*)d_in[4];
    const float* b_ih  = (const float*)d_in[5];
    const float* W_hh  = (const float*)d_in[6];
    const float* b_hh  = (const float*)d_in[7];
    const float* W_hid = (const float*)d_in[8];
    const float* b_hid = (const float*)d_in[9];
    float* out = (float*)d_out;
    (void)d_ws; (void)ws_size; (void)out_size; (void)n_in; (void)in_sizes;

    hipLaunchKernelGGL(ppo_lstm_scan, dim3(B_ENV / 2), dim3(1024), 0, stream,
                       x, done, h0, c0, W_ih, b_ih, W_hh, b_hh, out);
    hipLaunchKernelGGL(ppo_proj, dim3((T_STEPS * B_ENV) / H_DIM), dim3(256), 0, stream,
                       W_hid, b_hid, out);
}